// Round 4
// baseline (832.900 us; speedup 1.0000x reference)
//
#include <hip/hip_runtime.h>
#include <hip/hip_bf16.h>

typedef __attribute__((ext_vector_type(8))) short short8;
typedef __attribute__((ext_vector_type(4))) float f32x4;
typedef __hip_bfloat16 bf16_t;

#define SEQ 2048
#define DM 1024
#define NH 16
#define DK 64

static __device__ __forceinline__ f32x4 mfma16x16x32(short8 a, short8 b, f32x4 c) {
  return __builtin_amdgcn_mfma_f32_16x16x32_bf16(a, b, c, 0, 0, 0);
}

typedef __attribute__((address_space(3))) void lds_void;
typedef const __attribute__((address_space(1))) void gbl_void;
static __device__ __forceinline__ void async_cp16(const void* g, void* l) {
  __builtin_amdgcn_global_load_lds((gbl_void*)g, (lds_void*)l, 16, 0, 0);
}

// ---------------- dtype sniffer: flag=1 if buffers are bf16, 0 if fp32 ------
__global__ void sniff_dtype(const unsigned int* __restrict__ x, int* __restrict__ flag) {
  int lane = threadIdx.x & 63;
  int cnt = 0;
  for (int r = 0; r < 4; ++r) {
    unsigned int v = x[lane + r * 64];
    int e = (v >> 7) & 0xFF;
    if (e >= 100 && e <= 145) cnt++;
  }
  for (int d = 1; d < 64; d <<= 1) cnt += __shfl_xor(cnt, d, 64);
  if (lane == 0) *flag = (cnt >= 192) ? 1 : 0;
}

// ---------------- canonicalize x to bf16 ----------------
__global__ __launch_bounds__(256) void convert_x(const void* __restrict__ src,
                                                 bf16_t* __restrict__ dst,
                                                 const int* __restrict__ flag, int n4) {
  int f = *flag;
  int i = blockIdx.x * blockDim.x + threadIdx.x;
  if (i >= n4) return;
  if (f) {
    ((uint2*)dst)[i] = ((const uint2*)src)[i];
  } else {
    const float4 v = ((const float4*)src)[i];
    bf16_t o[4] = {__float2bfloat16(v.x), __float2bfloat16(v.y),
                   __float2bfloat16(v.z), __float2bfloat16(v.w)};
    ((uint2*)dst)[i] = *(const uint2*)o;
  }
}

// ---------------- transpose W (1024x1024) -> WT[n][k], dtype-dispatched -----
__global__ __launch_bounds__(256) void transpose_w(const void* __restrict__ w0,
                                                   const void* __restrict__ w1,
                                                   const void* __restrict__ w2,
                                                   const void* __restrict__ w3,
                                                   bf16_t* __restrict__ wt_base,
                                                   const int* __restrict__ flag) {
  int f = *flag;
  const void* src = (blockIdx.z == 0) ? w0 : (blockIdx.z == 1) ? w1
                  : (blockIdx.z == 2) ? w2 : w3;
  bf16_t* dst = wt_base + (size_t)blockIdx.z * DM * DM;
  __shared__ bf16_t tile[64][65];
  int t = threadIdx.x;
  int tx = t & 63, ty = t >> 6;
  int r0 = blockIdx.y * 64, c0 = blockIdx.x * 64;
  for (int i = 0; i < 64; i += 4) {
    size_t idx = (size_t)(r0 + ty + i) * DM + c0 + tx;
    tile[ty + i][tx] = f ? ((const bf16_t*)src)[idx]
                         : __float2bfloat16(((const float*)src)[idx]);
  }
  __syncthreads();
  for (int i = 0; i < 64; i += 4)
    dst[(size_t)(c0 + ty + i) * DM + r0 + tx] = tile[tx][ty + i];
}

// ---------------- fused QKV GEMM, 128x128 tile, global_load_lds ----------------
// A (4096x1024) @ WTqkv^T where WTqkv = [3072][1024] (q,k,v stacked along n).
// Q,K -> [B,NH,SEQ,DK] bf16 with RoPE; V -> [B*NH, DK, SEQ] (transposed, coalesced).
__global__ __launch_bounds__(256) void gemm128_qkv(const bf16_t* __restrict__ A,
                                                   const bf16_t* __restrict__ WTqkv,
                                                   bf16_t* __restrict__ Qo,
                                                   bf16_t* __restrict__ Ko,
                                                   bf16_t* __restrict__ VTo,
                                                   const int* __restrict__ tokpos) {
  __shared__ __align__(16) bf16_t As[128][32];
  __shared__ __align__(16) bf16_t Bs[128][32];
  __shared__ __align__(16) bf16_t T[64][80];
  int t = threadIdx.x;
  int w = t >> 6, lane = t & 63, l15 = lane & 15, quad = lane >> 4;
  int wrow = w >> 1, wcol = w & 1;
  int m0 = blockIdx.y * 128, n0 = blockIdx.x * 128;
  f32x4 acc[4][4] = {};
  for (int kk = 0; kk < DM; kk += 32) {
#pragma unroll
    for (int i = 0; i < 2; ++i) {
      int linear = i * 256 + t;
      int row = linear >> 2, cg = (linear & 3) * 8;
      async_cp16(A + (size_t)(m0 + row) * DM + kk + cg, &As[row][cg]);
      async_cp16(WTqkv + (size_t)(n0 + row) * DM + kk + cg, &Bs[row][cg]);
    }
    __syncthreads();
    short8 af[4], bfr[4];
#pragma unroll
    for (int mt = 0; mt < 4; ++mt) af[mt] = *(const short8*)&As[wrow * 64 + mt * 16 + l15][quad * 8];
#pragma unroll
    for (int nt = 0; nt < 4; ++nt) bfr[nt] = *(const short8*)&Bs[wcol * 64 + nt * 16 + l15][quad * 8];
#pragma unroll
    for (int mt = 0; mt < 4; ++mt)
#pragma unroll
      for (int nt = 0; nt < 4; ++nt)
        acc[mt][nt] = mfma16x16x32(af[mt], bfr[nt], acc[mt][nt]);
    __syncthreads();
  }

  int sel = n0 >> 10;      // 0=Q, 1=K, 2=V (tiles never straddle: 1024 % 128 == 0)
  int nc = n0 & 1023;
  if (sel < 2) {
    bf16_t* dst = sel ? Ko : Qo;
#pragma unroll
    for (int mt = 0; mt < 4; ++mt)
#pragma unroll
      for (int nt = 0; nt < 4; ++nt)
#pragma unroll
        for (int r = 0; r < 4; ++r) {
          int m = m0 + wrow * 64 + mt * 16 + quad * 4 + r;
          int col = nc + wcol * 64 + nt * 16 + l15;
          int h = col >> 6, d = col & 63;
          int b = m >> 11, s_idx = m & (SEQ - 1);
          float v = acc[mt][nt][r];
          float pv = __shfl_xor(v, 1, 64);
          int p = d >> 1;
          float invf = __powf(10000.0f, -(float)p * (1.0f / 32.0f));
          float ang = (float)tokpos[m] * invf;
          float sn, cs;
          sincosf(ang, &sn, &cs);
          float res = (d & 1) ? (pv * sn + v * cs) : (v * cs - pv * sn);
          dst[(((size_t)(b * NH + h)) * SEQ + s_idx) * DK + d] = __float2bfloat16(res);
        }
  } else {
    // V: transpose via LDS in 4 passes (rh = row half, hh = head half)
    int b = m0 >> 11;
    int s_base = m0 & (SEQ - 1);
#pragma unroll
    for (int rh = 0; rh < 2; ++rh)
#pragma unroll
      for (int hh = 0; hh < 2; ++hh) {
        if (wrow == rh && wcol == hh) {
#pragma unroll
          for (int mt = 0; mt < 4; ++mt)
#pragma unroll
            for (int nt = 0; nt < 4; ++nt)
#pragma unroll
              for (int r = 0; r < 4; ++r)
                T[nt * 16 + l15][mt * 16 + quad * 4 + r] = __float2bfloat16(acc[mt][nt][r]);
        }
        __syncthreads();
        int h = (nc >> 6) + hh;
        int drow = t >> 2, soff = (t & 3) * 16;
        size_t obase = ((size_t)(b * NH + h) * DK + drow) * SEQ + s_base + rh * 64 + soff;
        *(short8*)&VTo[obase] = *(const short8*)&T[drow][soff];
        *(short8*)&VTo[obase + 8] = *(const short8*)&T[drow][soff + 8];
        __syncthreads();
      }
  }
}

// ---------------- out-proj GEMM, 128x128 tile, global_load_lds --------------
__global__ __launch_bounds__(256) void gemm128_out(const bf16_t* __restrict__ A,
                                                   const bf16_t* __restrict__ BT,
                                                   void* __restrict__ out,
                                                   const int* __restrict__ flag) {
  __shared__ __align__(16) bf16_t As[128][32];
  __shared__ __align__(16) bf16_t Bs[128][32];
  int f = *flag;
  int t = threadIdx.x;
  int w = t >> 6, lane = t & 63, l15 = lane & 15, quad = lane >> 4;
  int wrow = w >> 1, wcol = w & 1;
  int m0 = blockIdx.y * 128, n0 = blockIdx.x * 128;
  f32x4 acc[4][4] = {};
  for (int kk = 0; kk < DM; kk += 32) {
#pragma unroll
    for (int i = 0; i < 2; ++i) {
      int linear = i * 256 + t;
      int row = linear >> 2, cg = (linear & 3) * 8;
      async_cp16(A + (size_t)(m0 + row) * DM + kk + cg, &As[row][cg]);
      async_cp16(BT + (size_t)(n0 + row) * DM + kk + cg, &Bs[row][cg]);
    }
    __syncthreads();
    short8 af[4], bfr[4];
#pragma unroll
    for (int mt = 0; mt < 4; ++mt) af[mt] = *(const short8*)&As[wrow * 64 + mt * 16 + l15][quad * 8];
#pragma unroll
    for (int nt = 0; nt < 4; ++nt) bfr[nt] = *(const short8*)&Bs[wcol * 64 + nt * 16 + l15][quad * 8];
#pragma unroll
    for (int mt = 0; mt < 4; ++mt)
#pragma unroll
      for (int nt = 0; nt < 4; ++nt)
        acc[mt][nt] = mfma16x16x32(af[mt], bfr[nt], acc[mt][nt]);
    __syncthreads();
  }
#pragma unroll
  for (int mt = 0; mt < 4; ++mt)
#pragma unroll
    for (int nt = 0; nt < 4; ++nt)
#pragma unroll
      for (int r = 0; r < 4; ++r) {
        int m = m0 + wrow * 64 + mt * 16 + quad * 4 + r;
        int col = n0 + wcol * 64 + nt * 16 + l15;
        size_t oidx = (size_t)m * DM + col;
        if (f) ((bf16_t*)out)[oidx] = __float2bfloat16(acc[mt][nt][r]);
        else   ((float*)out)[oidx] = acc[mt][nt][r];
      }
}

// ---------------- causal flash attention, heavy-first, barrier-free ---------
// Q,K: [B*NH, SEQ, DK]; VT: [B*NH, DK, SEQ]. Out: [B, SEQ, DM].
// Block bx handles q-tile qb = 31-bx (heavy blocks dispatch first).
__global__ __launch_bounds__(256) void attn_fwd(const bf16_t* __restrict__ Q,
                                                const bf16_t* __restrict__ K,
                                                const bf16_t* __restrict__ VT,
                                                bf16_t* __restrict__ O) {
  int qb = 31 - blockIdx.x, bh = blockIdx.y;
  int b = bh >> 4, h = bh & 15;
  int t = threadIdx.x;
  int w = t >> 6, lane = t & 63, l15 = lane & 15, quad = lane >> 4;
  const size_t base = (size_t)bh * SEQ * DK;
  const bf16_t* Qp = Q + base;
  const bf16_t* Kp = K + base;
  const bf16_t* VTp = VT + base;  // [DK][SEQ]

  __shared__ __align__(16) bf16_t Pb[4][16][72];  // per-wave P buffer

  int qrow = qb * 64 + w * 16 + l15;
  short8 qf0 = *(const short8*)(Qp + (size_t)qrow * DK + quad * 8);
  short8 qf1 = *(const short8*)(Qp + (size_t)qrow * DK + 32 + quad * 8);

  f32x4 oacc[4] = {};
  float m_run[4], l_run[4];
#pragma unroll
  for (int r = 0; r < 4; ++r) { m_run[r] = -30000.0f; l_run[r] = 0.0f; }

  short8 kf0[4], kf1[4], kn0[4], kn1[4], vf0[4], vf1[4];
#pragma unroll
  for (int kt = 0; kt < 4; ++kt) {
    const bf16_t* kr = Kp + (size_t)(kt * 16 + l15) * DK;
    kf0[kt] = *(const short8*)(kr + quad * 8);
    kf1[kt] = *(const short8*)(kr + 32 + quad * 8);
  }

  for (int kb = 0; kb <= qb; ++kb) {
#pragma unroll
    for (int dt = 0; dt < 4; ++dt) {
      const bf16_t* vr = VTp + (size_t)(dt * 16 + l15) * SEQ + kb * 64;
      vf0[dt] = *(const short8*)(vr + quad * 8);
      vf1[dt] = *(const short8*)(vr + 32 + quad * 8);
    }
    f32x4 sc[4];
#pragma unroll
    for (int kt = 0; kt < 4; ++kt) {
      f32x4 a = {};
      a = mfma16x16x32(qf0, kf0[kt], a);
      a = mfma16x16x32(qf1, kf1[kt], a);
      sc[kt] = a;
    }
    if (kb < qb) {
#pragma unroll
      for (int kt = 0; kt < 4; ++kt) {
        const bf16_t* kr = Kp + (size_t)((kb + 1) * 64 + kt * 16 + l15) * DK;
        kn0[kt] = *(const short8*)(kr + quad * 8);
        kn1[kt] = *(const short8*)(kr + 32 + quad * 8);
      }
    }
#pragma unroll
    for (int kt = 0; kt < 4; ++kt)
#pragma unroll
      for (int reg = 0; reg < 4; ++reg) {
        float sv = sc[kt][reg] * 0.125f;
        if (kb == qb) {
          int kg = kt * 16 + l15;
          int qg = w * 16 + quad * 4 + reg;
          if (kg > qg) sv = -30000.0f;
        }
        sc[kt][reg] = sv;
      }
    float mx[4];
#pragma unroll
    for (int reg = 0; reg < 4; ++reg)
      mx[reg] = fmaxf(fmaxf(sc[0][reg], sc[1][reg]), fmaxf(sc[2][reg], sc[3][reg]));
    for (int d = 1; d < 16; d <<= 1)
#pragma unroll
      for (int reg = 0; reg < 4; ++reg)
        mx[reg] = fmaxf(mx[reg], __shfl_xor(mx[reg], d, 64));

    float alpha[4];
#pragma unroll
    for (int reg = 0; reg < 4; ++reg) {
      float mn = fmaxf(m_run[reg], mx[reg]);
      alpha[reg] = __expf(m_run[reg] - mn);
      m_run[reg] = mn;
    }
    float rs[4] = {0.f, 0.f, 0.f, 0.f};
#pragma unroll
    for (int kt = 0; kt < 4; ++kt)
#pragma unroll
      for (int reg = 0; reg < 4; ++reg) {
        float pp = __expf(sc[kt][reg] - m_run[reg]);
        rs[reg] += pp;
        Pb[w][quad * 4 + reg][kt * 16 + l15] = __float2bfloat16(pp);
      }
    for (int d = 1; d < 16; d <<= 1)
#pragma unroll
      for (int reg = 0; reg < 4; ++reg)
        rs[reg] += __shfl_xor(rs[reg], d, 64);
#pragma unroll
    for (int reg = 0; reg < 4; ++reg)
      l_run[reg] = l_run[reg] * alpha[reg] + rs[reg];
#pragma unroll
    for (int dt = 0; dt < 4; ++dt)
#pragma unroll
      for (int reg = 0; reg < 4; ++reg)
        oacc[dt][reg] *= alpha[reg];

    short8 pf0 = *(const short8*)&Pb[w][l15][quad * 8];
    short8 pf1 = *(const short8*)&Pb[w][l15][32 + quad * 8];
#pragma unroll
    for (int dt = 0; dt < 4; ++dt) {
      oacc[dt] = mfma16x16x32(pf0, vf0[dt], oacc[dt]);
      oacc[dt] = mfma16x16x32(pf1, vf1[dt], oacc[dt]);
    }
    if (kb < qb) {
#pragma unroll
      for (int kt = 0; kt < 4; ++kt) { kf0[kt] = kn0[kt]; kf1[kt] = kn1[kt]; }
    }
  }

#pragma unroll
  for (int dt = 0; dt < 4; ++dt)
#pragma unroll
    for (int reg = 0; reg < 4; ++reg) {
      int q = qb * 64 + w * 16 + quad * 4 + reg;
      float v = oacc[dt][reg] / l_run[reg];
      O[((size_t)b * SEQ + q) * DM + h * DK + dt * 16 + l15] = __float2bfloat16(v);
    }
}

extern "C" void kernel_launch(void* const* d_in, const int* in_sizes, int n_in,
                              void* d_out, int out_size, void* d_ws, size_t ws_size,
                              hipStream_t stream) {
  const void* x = d_in[0];
  const int* tokpos = (const int*)d_in[1];
  const void* WQ = d_in[2];
  const void* WK = d_in[3];
  const void* WV = d_in[4];
  const void* WO = d_in[5];

  char* ws = (char*)d_ws;
  const size_t MB = 1024 * 1024;
  bf16_t* WT = (bf16_t*)ws;                    // 8 MB (4 x 1024x1024 bf16; q,k,v,o)
  bf16_t* Qb = (bf16_t*)(ws + 8 * MB);         // 8 MB
  bf16_t* Kb = (bf16_t*)(ws + 16 * MB);        // 8 MB
  bf16_t* VTb = (bf16_t*)(ws + 24 * MB);       // 8 MB, [B*NH, DK, SEQ]
  bf16_t* Xc = (bf16_t*)(ws + 32 * MB);        // 8 MB (canonical bf16 x; reused as Ab)
  bf16_t* Ab = Xc;                             // attn out reuses Xc after last read
  int* flag  = (int*)(ws + 40 * MB);

  dim3 blk(256);
  sniff_dtype<<<1, 64, 0, stream>>>((const unsigned int*)x, flag);
  convert_x<<<4096, blk, 0, stream>>>(x, Xc, flag, (SEQ * 2 * DM) / 4);
  transpose_w<<<dim3(16, 16, 4), blk, 0, stream>>>(WQ, WK, WV, WO, WT, flag);
  gemm128_qkv<<<dim3(24, 32), blk, 0, stream>>>(Xc, WT, Qb, Kb, VTb, tokpos);
  attn_fwd<<<dim3(32, 32), blk, 0, stream>>>(Qb, Kb, VTb, Ab);
  gemm128_out<<<dim3(8, 32), blk, 0, stream>>>(Ab, WT + (size_t)3 * DM * DM, d_out, flag);
}

// Round 5
// 821.589 us; speedup vs baseline: 1.0138x; 1.0138x over previous
//
#include <hip/hip_runtime.h>
#include <hip/hip_bf16.h>

typedef __attribute__((ext_vector_type(8))) short short8;
typedef __attribute__((ext_vector_type(4))) float f32x4;
typedef __hip_bfloat16 bf16_t;

#define SEQ 2048
#define DM 1024
#define NH 16
#define DK 64

static __device__ __forceinline__ f32x4 mfma16x16x32(short8 a, short8 b, f32x4 c) {
  return __builtin_amdgcn_mfma_f32_16x16x32_bf16(a, b, c, 0, 0, 0);
}

typedef __attribute__((address_space(3))) void lds_void;
typedef const __attribute__((address_space(1))) void gbl_void;
static __device__ __forceinline__ void async_cp16(const void* g, void* l) {
  __builtin_amdgcn_global_load_lds((gbl_void*)g, (lds_void*)l, 16, 0, 0);
}

// ---------------- dtype sniffer: flag=1 if buffers are bf16, 0 if fp32 ------
__global__ void sniff_dtype(const unsigned int* __restrict__ x, int* __restrict__ flag) {
  int lane = threadIdx.x & 63;
  int cnt = 0;
  for (int r = 0; r < 4; ++r) {
    unsigned int v = x[lane + r * 64];
    int e = (v >> 7) & 0xFF;
    if (e >= 100 && e <= 145) cnt++;
  }
  for (int d = 1; d < 64; d <<= 1) cnt += __shfl_xor(cnt, d, 64);
  if (lane == 0) *flag = (cnt >= 192) ? 1 : 0;
}

// ---------------- canonicalize x to bf16 ----------------
__global__ __launch_bounds__(256) void convert_x(const void* __restrict__ src,
                                                 bf16_t* __restrict__ dst,
                                                 const int* __restrict__ flag, int n4) {
  int f = *flag;
  int i = blockIdx.x * blockDim.x + threadIdx.x;
  if (i >= n4) return;
  if (f) {
    ((uint2*)dst)[i] = ((const uint2*)src)[i];
  } else {
    const float4 v = ((const float4*)src)[i];
    bf16_t o[4] = {__float2bfloat16(v.x), __float2bfloat16(v.y),
                   __float2bfloat16(v.z), __float2bfloat16(v.w)};
    ((uint2*)dst)[i] = *(const uint2*)o;
  }
}

// ---------------- transpose W (1024x1024) -> WT[n][k], dtype-dispatched -----
__global__ __launch_bounds__(256) void transpose_w(const void* __restrict__ w0,
                                                   const void* __restrict__ w1,
                                                   const void* __restrict__ w2,
                                                   const void* __restrict__ w3,
                                                   bf16_t* __restrict__ wt_base,
                                                   const int* __restrict__ flag) {
  int f = *flag;
  const void* src = (blockIdx.z == 0) ? w0 : (blockIdx.z == 1) ? w1
                  : (blockIdx.z == 2) ? w2 : w3;
  bf16_t* dst = wt_base + (size_t)blockIdx.z * DM * DM;
  __shared__ bf16_t tile[64][65];
  int t = threadIdx.x;
  int tx = t & 63, ty = t >> 6;
  int r0 = blockIdx.y * 64, c0 = blockIdx.x * 64;
  for (int i = 0; i < 64; i += 4) {
    size_t idx = (size_t)(r0 + ty + i) * DM + c0 + tx;
    tile[ty + i][tx] = f ? ((const bf16_t*)src)[idx]
                         : __float2bfloat16(((const float*)src)[idx]);
  }
  __syncthreads();
  for (int i = 0; i < 64; i += 4)
    dst[(size_t)(c0 + ty + i) * DM + r0 + tx] = tile[tx][ty + i];
}

// ---------------- fused QKV GEMM, 128x128 tile, XCD-swizzled ----------------
// A (4096x1024) @ WTqkv^T where WTqkv = [3072][1024] (q,k,v stacked along n).
// Grid: 768 blocks 1-D. XCD x (= linear%8) gets an 8m x 12n tile rectangle so
// its 4 MiB L2 holds the rectangle's A-strip (2 MB) + W-strip (3 MB).
__global__ __launch_bounds__(256) void gemm128_qkv(const bf16_t* __restrict__ A,
                                                   const bf16_t* __restrict__ WTqkv,
                                                   bf16_t* __restrict__ Qo,
                                                   bf16_t* __restrict__ Ko,
                                                   bf16_t* __restrict__ VTo,
                                                   const int* __restrict__ tokpos) {
  __shared__ __align__(16) bf16_t As[128][32];
  __shared__ __align__(16) bf16_t Bs[128][32];
  __shared__ __align__(16) bf16_t T[64][80];
  int t = threadIdx.x;
  int w = t >> 6, lane = t & 63, l15 = lane & 15, quad = lane >> 4;
  int wrow = w >> 1, wcol = w & 1;
  int l = blockIdx.x;
  int xcd = l & 7, s = l >> 3;                 // s in [0,96)
  int mt_idx = (xcd >> 1) * 8 + (s & 7);       // [0,32)
  int nt_idx = (xcd & 1) * 12 + (s >> 3);      // [0,24)
  int m0 = mt_idx * 128, n0 = nt_idx * 128;
  f32x4 acc[4][4] = {};
  for (int kk = 0; kk < DM; kk += 32) {
#pragma unroll
    for (int i = 0; i < 2; ++i) {
      int linear = i * 256 + t;
      int row = linear >> 2, cg = (linear & 3) * 8;
      async_cp16(A + (size_t)(m0 + row) * DM + kk + cg, &As[row][cg]);
      async_cp16(WTqkv + (size_t)(n0 + row) * DM + kk + cg, &Bs[row][cg]);
    }
    __syncthreads();
    short8 af[4], bfr[4];
#pragma unroll
    for (int mt = 0; mt < 4; ++mt) af[mt] = *(const short8*)&As[wrow * 64 + mt * 16 + l15][quad * 8];
#pragma unroll
    for (int nt = 0; nt < 4; ++nt) bfr[nt] = *(const short8*)&Bs[wcol * 64 + nt * 16 + l15][quad * 8];
#pragma unroll
    for (int mt = 0; mt < 4; ++mt)
#pragma unroll
      for (int nt = 0; nt < 4; ++nt)
        acc[mt][nt] = mfma16x16x32(af[mt], bfr[nt], acc[mt][nt]);
    __syncthreads();
  }

  int sel = n0 >> 10;      // 0=Q, 1=K, 2=V (tiles never straddle: 1024 % 128 == 0)
  int nc = n0 & 1023;
  if (sel < 2) {
    bf16_t* dst = sel ? Ko : Qo;
#pragma unroll
    for (int mt = 0; mt < 4; ++mt)
#pragma unroll
      for (int nt = 0; nt < 4; ++nt)
#pragma unroll
        for (int r = 0; r < 4; ++r) {
          int m = m0 + wrow * 64 + mt * 16 + quad * 4 + r;
          int col = nc + wcol * 64 + nt * 16 + l15;
          int h = col >> 6, d = col & 63;
          int b = m >> 11, s_idx = m & (SEQ - 1);
          float v = acc[mt][nt][r];
          float pv = __shfl_xor(v, 1, 64);
          int p = d >> 1;
          float invf = __powf(10000.0f, -(float)p * (1.0f / 32.0f));
          float ang = (float)tokpos[m] * invf;
          float sn, cs;
          sincosf(ang, &sn, &cs);
          float res = (d & 1) ? (pv * sn + v * cs) : (v * cs - pv * sn);
          dst[(((size_t)(b * NH + h)) * SEQ + s_idx) * DK + d] = __float2bfloat16(res);
        }
  } else {
    // V: transpose via LDS in 4 passes (rh = row half, hh = head half)
    int b = m0 >> 11;
    int s_base = m0 & (SEQ - 1);
#pragma unroll
    for (int rh = 0; rh < 2; ++rh)
#pragma unroll
      for (int hh = 0; hh < 2; ++hh) {
        if (wrow == rh && wcol == hh) {
#pragma unroll
          for (int mt = 0; mt < 4; ++mt)
#pragma unroll
            for (int nt = 0; nt < 4; ++nt)
#pragma unroll
              for (int r = 0; r < 4; ++r)
                T[nt * 16 + l15][mt * 16 + quad * 4 + r] = __float2bfloat16(acc[mt][nt][r]);
        }
        __syncthreads();
        int h = (nc >> 6) + hh;
        int drow = t >> 2, soff = (t & 3) * 16;
        size_t obase = ((size_t)(b * NH + h) * DK + drow) * SEQ + s_base + rh * 64 + soff;
        *(short8*)&VTo[obase] = *(const short8*)&T[drow][soff];
        *(short8*)&VTo[obase + 8] = *(const short8*)&T[drow][soff + 8];
        __syncthreads();
      }
  }
}

// ---------------- out-proj GEMM, 128x128 tile, XCD-swizzled ----------------
// Grid: 256 blocks 1-D. XCD x gets 4 m-tiles x all 8 n-tiles (A 1MB + B 2MB in L2).
__global__ __launch_bounds__(256) void gemm128_out(const bf16_t* __restrict__ A,
                                                   const bf16_t* __restrict__ BT,
                                                   void* __restrict__ out,
                                                   const int* __restrict__ flag) {
  __shared__ __align__(16) bf16_t As[128][32];
  __shared__ __align__(16) bf16_t Bs[128][32];
  int f = *flag;
  int t = threadIdx.x;
  int w = t >> 6, lane = t & 63, l15 = lane & 15, quad = lane >> 4;
  int wrow = w >> 1, wcol = w & 1;
  int l = blockIdx.x;
  int xcd = l & 7, s = l >> 3;                 // s in [0,32)
  int m0 = (xcd * 4 + (s & 3)) * 128;
  int n0 = (s >> 2) * 128;
  f32x4 acc[4][4] = {};
  for (int kk = 0; kk < DM; kk += 32) {
#pragma unroll
    for (int i = 0; i < 2; ++i) {
      int linear = i * 256 + t;
      int row = linear >> 2, cg = (linear & 3) * 8;
      async_cp16(A + (size_t)(m0 + row) * DM + kk + cg, &As[row][cg]);
      async_cp16(BT + (size_t)(n0 + row) * DM + kk + cg, &Bs[row][cg]);
    }
    __syncthreads();
    short8 af[4], bfr[4];
#pragma unroll
    for (int mt = 0; mt < 4; ++mt) af[mt] = *(const short8*)&As[wrow * 64 + mt * 16 + l15][quad * 8];
#pragma unroll
    for (int nt = 0; nt < 4; ++nt) bfr[nt] = *(const short8*)&Bs[wcol * 64 + nt * 16 + l15][quad * 8];
#pragma unroll
    for (int mt = 0; mt < 4; ++mt)
#pragma unroll
      for (int nt = 0; nt < 4; ++nt)
        acc[mt][nt] = mfma16x16x32(af[mt], bfr[nt], acc[mt][nt]);
    __syncthreads();
  }
#pragma unroll
  for (int mt = 0; mt < 4; ++mt)
#pragma unroll
    for (int nt = 0; nt < 4; ++nt)
#pragma unroll
      for (int r = 0; r < 4; ++r) {
        int m = m0 + wrow * 64 + mt * 16 + quad * 4 + r;
        int col = n0 + wcol * 64 + nt * 16 + l15;
        size_t oidx = (size_t)m * DM + col;
        if (f) ((bf16_t*)out)[oidx] = __float2bfloat16(acc[mt][nt][r]);
        else   ((float*)out)[oidx] = acc[mt][nt][r];
      }
}

// ---------------- causal flash attention, heavy-first, barrier-free ---------
// Q,K: [B*NH, SEQ, DK]; VT: [B*NH, DK, SEQ]. Out: [B, SEQ, DM].
// Block bx handles q-tile qb = 31-bx (heavy blocks dispatch first).
__global__ __launch_bounds__(256) void attn_fwd(const bf16_t* __restrict__ Q,
                                                const bf16_t* __restrict__ K,
                                                const bf16_t* __restrict__ VT,
                                                bf16_t* __restrict__ O) {
  int qb = 31 - blockIdx.x, bh = blockIdx.y;
  int b = bh >> 4, h = bh & 15;
  int t = threadIdx.x;
  int w = t >> 6, lane = t & 63, l15 = lane & 15, quad = lane >> 4;
  const size_t base = (size_t)bh * SEQ * DK;
  const bf16_t* Qp = Q + base;
  const bf16_t* Kp = K + base;
  const bf16_t* VTp = VT + base;  // [DK][SEQ]

  __shared__ __align__(16) bf16_t Pb[4][16][72];  // per-wave P buffer

  int qrow = qb * 64 + w * 16 + l15;
  short8 qf0 = *(const short8*)(Qp + (size_t)qrow * DK + quad * 8);
  short8 qf1 = *(const short8*)(Qp + (size_t)qrow * DK + 32 + quad * 8);

  f32x4 oacc[4] = {};
  float m_run[4], l_run[4];
#pragma unroll
  for (int r = 0; r < 4; ++r) { m_run[r] = -30000.0f; l_run[r] = 0.0f; }

  short8 kf0[4], kf1[4], kn0[4], kn1[4], vf0[4], vf1[4];
#pragma unroll
  for (int kt = 0; kt < 4; ++kt) {
    const bf16_t* kr = Kp + (size_t)(kt * 16 + l15) * DK;
    kf0[kt] = *(const short8*)(kr + quad * 8);
    kf1[kt] = *(const short8*)(kr + 32 + quad * 8);
  }

  for (int kb = 0; kb <= qb; ++kb) {
#pragma unroll
    for (int dt = 0; dt < 4; ++dt) {
      const bf16_t* vr = VTp + (size_t)(dt * 16 + l15) * SEQ + kb * 64;
      vf0[dt] = *(const short8*)(vr + quad * 8);
      vf1[dt] = *(const short8*)(vr + 32 + quad * 8);
    }
    f32x4 sc[4];
#pragma unroll
    for (int kt = 0; kt < 4; ++kt) {
      f32x4 a = {};
      a = mfma16x16x32(qf0, kf0[kt], a);
      a = mfma16x16x32(qf1, kf1[kt], a);
      sc[kt] = a;
    }
    if (kb < qb) {
#pragma unroll
      for (int kt = 0; kt < 4; ++kt) {
        const bf16_t* kr = Kp + (size_t)((kb + 1) * 64 + kt * 16 + l15) * DK;
        kn0[kt] = *(const short8*)(kr + quad * 8);
        kn1[kt] = *(const short8*)(kr + 32 + quad * 8);
      }
    }
#pragma unroll
    for (int kt = 0; kt < 4; ++kt)
#pragma unroll
      for (int reg = 0; reg < 4; ++reg) {
        float sv = sc[kt][reg] * 0.125f;
        if (kb == qb) {
          int kg = kt * 16 + l15;
          int qg = w * 16 + quad * 4 + reg;
          if (kg > qg) sv = -30000.0f;
        }
        sc[kt][reg] = sv;
      }
    float mx[4];
#pragma unroll
    for (int reg = 0; reg < 4; ++reg)
      mx[reg] = fmaxf(fmaxf(sc[0][reg], sc[1][reg]), fmaxf(sc[2][reg], sc[3][reg]));
    for (int d = 1; d < 16; d <<= 1)
#pragma unroll
      for (int reg = 0; reg < 4; ++reg)
        mx[reg] = fmaxf(mx[reg], __shfl_xor(mx[reg], d, 64));

    float alpha[4];
#pragma unroll
    for (int reg = 0; reg < 4; ++reg) {
      float mn = fmaxf(m_run[reg], mx[reg]);
      alpha[reg] = __expf(m_run[reg] - mn);
      m_run[reg] = mn;
    }
    float rs[4] = {0.f, 0.f, 0.f, 0.f};
#pragma unroll
    for (int kt = 0; kt < 4; ++kt)
#pragma unroll
      for (int reg = 0; reg < 4; ++reg) {
        float pp = __expf(sc[kt][reg] - m_run[reg]);
        rs[reg] += pp;
        Pb[w][quad * 4 + reg][kt * 16 + l15] = __float2bfloat16(pp);
      }
    for (int d = 1; d < 16; d <<= 1)
#pragma unroll
      for (int reg = 0; reg < 4; ++reg)
        rs[reg] += __shfl_xor(rs[reg], d, 64);
#pragma unroll
    for (int reg = 0; reg < 4; ++reg)
      l_run[reg] = l_run[reg] * alpha[reg] + rs[reg];
#pragma unroll
    for (int dt = 0; dt < 4; ++dt)
#pragma unroll
      for (int reg = 0; reg < 4; ++reg)
        oacc[dt][reg] *= alpha[reg];

    short8 pf0 = *(const short8*)&Pb[w][l15][quad * 8];
    short8 pf1 = *(const short8*)&Pb[w][l15][32 + quad * 8];
#pragma unroll
    for (int dt = 0; dt < 4; ++dt) {
      oacc[dt] = mfma16x16x32(pf0, vf0[dt], oacc[dt]);
      oacc[dt] = mfma16x16x32(pf1, vf1[dt], oacc[dt]);
    }
    if (kb < qb) {
#pragma unroll
      for (int kt = 0; kt < 4; ++kt) { kf0[kt] = kn0[kt]; kf1[kt] = kn1[kt]; }
    }
  }

#pragma unroll
  for (int dt = 0; dt < 4; ++dt)
#pragma unroll
    for (int reg = 0; reg < 4; ++reg) {
      int q = qb * 64 + w * 16 + quad * 4 + reg;
      float v = oacc[dt][reg] / l_run[reg];
      O[((size_t)b * SEQ + q) * DM + h * DK + dt * 16 + l15] = __float2bfloat16(v);
    }
}

extern "C" void kernel_launch(void* const* d_in, const int* in_sizes, int n_in,
                              void* d_out, int out_size, void* d_ws, size_t ws_size,
                              hipStream_t stream) {
  const void* x = d_in[0];
  const int* tokpos = (const int*)d_in[1];
  const void* WQ = d_in[2];
  const void* WK = d_in[3];
  const void* WV = d_in[4];
  const void* WO = d_in[5];

  char* ws = (char*)d_ws;
  const size_t MB = 1024 * 1024;
  bf16_t* WT = (bf16_t*)ws;                    // 8 MB (4 x 1024x1024 bf16; q,k,v,o)
  bf16_t* Qb = (bf16_t*)(ws + 8 * MB);         // 8 MB
  bf16_t* Kb = (bf16_t*)(ws + 16 * MB);        // 8 MB
  bf16_t* VTb = (bf16_t*)(ws + 24 * MB);       // 8 MB, [B*NH, DK, SEQ]
  bf16_t* Xc = (bf16_t*)(ws + 32 * MB);        // 8 MB (canonical bf16 x; reused as Ab)
  bf16_t* Ab = Xc;                             // attn out reuses Xc after last read
  int* flag  = (int*)(ws + 40 * MB);

  dim3 blk(256);
  sniff_dtype<<<1, 64, 0, stream>>>((const unsigned int*)x, flag);
  convert_x<<<4096, blk, 0, stream>>>(x, Xc, flag, (SEQ * 2 * DM) / 4);
  transpose_w<<<dim3(16, 16, 4), blk, 0, stream>>>(WQ, WK, WV, WO, WT, flag);
  gemm128_qkv<<<dim3(768), blk, 0, stream>>>(Xc, WT, Qb, Kb, VTb, tokpos);
  attn_fwd<<<dim3(32, 32), blk, 0, stream>>>(Qb, Kb, VTb, Ab);
  gemm128_out<<<dim3(256), blk, 0, stream>>>(Ab, WT + (size_t)3 * DM * DM, d_out, flag);
}